// Round 3
// baseline (631.099 us; speedup 1.0000x reference)
//
#include <hip/hip_runtime.h>

typedef unsigned short ushort_t;
typedef unsigned int uint32;
typedef __bf16 bf16x8 __attribute__((ext_vector_type(8)));
typedef float f32x4 __attribute__((ext_vector_type(4)));
typedef uint32 u32x4 __attribute__((ext_vector_type(4)));

__device__ __forceinline__ float bf2f(ushort_t u) {
    uint32 x = ((uint32)u) << 16;
    return __builtin_bit_cast(float, x);
}
__device__ __forceinline__ ushort_t f2bf(float f) {
    uint32 x = __builtin_bit_cast(uint32, f);
    x += 0x7fffu + ((x >> 16) & 1u);   // round-to-nearest-even
    return (ushort_t)(x >> 16);
}

// dtype sniffer: low u16 of each u32 word of a N(0,1) tensor. bf16 world:
// it's a bf16 normal, exp field in [~96,130]. f32 world: low mantissa bits,
// exp field uniform -> ~50% outside [64,192).
__global__ void sniff_kernel(const uint32* __restrict__ src, int* __restrict__ flag) {
    __shared__ int cnt;
    if (threadIdx.x == 0) cnt = 0;
    __syncthreads();
    int weird = 0;
    for (int c = 0; c < 4; c++) {
        uint32 w = src[threadIdx.x * 4 + c];
        uint32 e = (w >> 7) & 0xFFu;
        weird += (e < 64u) || (e >= 192u);
    }
    atomicAdd(&cnt, weird);
    __syncthreads();
    if (threadIdx.x == 0) *flag = (cnt > 32) ? 1 : 0;   // 1 = f32 inputs
}

__global__ void canon_kernel(const void* __restrict__ src, ushort_t* __restrict__ dst,
                             long n, const int* __restrict__ flag) {
    const bool isf32 = (*flag != 0);
    long i = (long)blockIdx.x * blockDim.x + threadIdx.x;
    const long stride = (long)gridDim.x * blockDim.x;
    if (isf32) {
        const float* s = (const float*)src;
        for (; i < n; i += stride) dst[i] = f2bf(s[i]);
    } else {
        const ushort_t* s = (const ushort_t*)src;
        for (; i < n; i += stride) dst[i] = s[i];
    }
}

#define BM 128
#define BN 128
#define BK 32
#define LDSS 40

enum { EPI_BIAS = 0, EPI_PLAIN = 1, EPI_SCALE = 2, EPI_BN = 3 };

// C[M,N] = op(A) @ op(B) (+ epilogue). A,B bf16; fp32 accum.
// DYNOUT: output dtype (f32/bf16) chosen at runtime via *flag; else bf16.
// coff: flat ELEMENT offset of this output inside Cv (dtype-independent).
template <bool TA, bool TB, int EPI, bool DYNOUT>
__global__ __launch_bounds__(256) void gemm_kernel(
    const ushort_t* __restrict__ A, const ushort_t* __restrict__ B,
    void* __restrict__ Cv, long coff,
    int M, int N, int K, int lda, int ldb, int ldc,
    long sA, long sB, long sC,
    const ushort_t* __restrict__ bias,
    const ushort_t* __restrict__ gamma, const ushort_t* __restrict__ beta,
    const ushort_t* __restrict__ mean, const ushort_t* __restrict__ var,
    const ushort_t* __restrict__ res,
    float alpha, const int* __restrict__ flag)
{
    __shared__ __align__(16) ushort_t As[BM * LDSS];
    __shared__ __align__(16) ushort_t Bs[BN * LDSS];

    const bool isf32 = DYNOUT ? (*flag != 0) : false;

    const int b = blockIdx.z;
    A += (long)b * sA;
    B += (long)b * sB;
    const long cbase = coff + (long)b * sC;

    const int tid  = threadIdx.x;
    const int lane = tid & 63;
    const int w    = tid >> 6;
    const int wr   = w >> 1, wc = w & 1;
    const int lr   = lane & 15, q = lane >> 4;

    const int m0 = blockIdx.y * BM;
    const int n0 = blockIdx.x * BN;

    f32x4 acc[4][4];
#pragma unroll
    for (int i = 0; i < 4; i++)
#pragma unroll
        for (int j = 0; j < 4; j++) acc[i][j] = (f32x4){0.f, 0.f, 0.f, 0.f};

    for (int k0 = 0; k0 < K; k0 += BK) {
        if constexpr (!TA) {
#pragma unroll
            for (int c = 0; c < 2; c++) {
                const int ch = tid + c * 256;
                const int r = ch >> 2, qq = ch & 3;
                const u32x4 v = *(const u32x4*)(A + (long)(m0 + r) * lda + k0 + qq * 8);
                *(u32x4*)(&As[r * LDSS + qq * 8]) = v;
            }
        } else {
#pragma unroll
            for (int c = 0; c < 2; c++) {
                const int ch = tid + c * 256;
                const int kk = ch & 31, mc = ch >> 5;
                const u32x4 v = *(const u32x4*)(A + (long)(k0 + kk) * lda + m0 + mc * 8);
                const ushort_t* pv = (const ushort_t*)&v;
#pragma unroll
                for (int i = 0; i < 8; i++) As[(mc * 8 + i) * LDSS + kk] = pv[i];
            }
        }
        if constexpr (TB) {
#pragma unroll
            for (int c = 0; c < 2; c++) {
                const int ch = tid + c * 256;
                const int r = ch >> 2, qq = ch & 3;
                const u32x4 v = *(const u32x4*)(B + (long)(n0 + r) * ldb + k0 + qq * 8);
                *(u32x4*)(&Bs[r * LDSS + qq * 8]) = v;
            }
        } else {
#pragma unroll
            for (int c = 0; c < 2; c++) {
                const int ch = tid + c * 256;
                const int kk = ch & 31, nc = ch >> 5;
                const u32x4 v = *(const u32x4*)(B + (long)(k0 + kk) * ldb + n0 + nc * 8);
                const ushort_t* pv = (const ushort_t*)&v;
#pragma unroll
                for (int i = 0; i < 8; i++) Bs[(nc * 8 + i) * LDSS + kk] = pv[i];
            }
        }
        __syncthreads();

        bf16x8 af[4], bfr[4];
#pragma unroll
        for (int i = 0; i < 4; i++)
            af[i] = __builtin_bit_cast(bf16x8,
                *(const u32x4*)(&As[(wr * 64 + i * 16 + lr) * LDSS + q * 8]));
#pragma unroll
        for (int j = 0; j < 4; j++)
            bfr[j] = __builtin_bit_cast(bf16x8,
                *(const u32x4*)(&Bs[(wc * 64 + j * 16 + lr) * LDSS + q * 8]));
#pragma unroll
        for (int i = 0; i < 4; i++)
#pragma unroll
            for (int j = 0; j < 4; j++)
                acc[i][j] = __builtin_amdgcn_mfma_f32_16x16x32_bf16(af[i], bfr[j], acc[i][j], 0, 0, 0);
        __syncthreads();
    }

#pragma unroll
    for (int j = 0; j < 4; j++) {
        const int col = n0 + wc * 64 + j * 16 + lr;
        float bs = 0.f, sc = 1.f, sh = 0.f;
        if constexpr (EPI == EPI_BIAS || EPI == EPI_BN) bs = bf2f(bias[col]);
        if constexpr (EPI == EPI_BN) {
            const float g  = bf2f(gamma[col]);
            const float bt = bf2f(beta[col]);
            const float mn = bf2f(mean[col]);
            const float vr = bf2f(var[col]);
            sc = g * rsqrtf(vr + 1e-3f);
            sh = bt - sc * mn;
        }
#pragma unroll
        for (int i = 0; i < 4; i++) {
#pragma unroll
            for (int r = 0; r < 4; r++) {
                const int row = m0 + wr * 64 + i * 16 + q * 4 + r;
                float v = acc[i][j][r];
                if constexpr (EPI == EPI_BIAS) v += bs;
                else if constexpr (EPI == EPI_SCALE) v *= alpha;
                else if constexpr (EPI == EPI_BN)
                    v = sc * (v + bs) + sh + bf2f(res[(long)row * ldc + col]);
                const long off = cbase + (long)row * ldc + col;
                if constexpr (DYNOUT) {
                    if (isf32) ((float*)Cv)[off] = v;
                    else       ((ushort_t*)Cv)[off] = f2bf(v);
                } else {
                    ((ushort_t*)Cv)[off] = f2bf(v);
                }
            }
        }
    }
}

extern "C" void kernel_launch(void* const* d_in, const int* in_sizes, int n_in,
                              void* d_out, int out_size, void* d_ws, size_t ws_size,
                              hipStream_t stream)
{
    int* flag = (int*)d_ws;
    ushort_t* base = (ushort_t*)((char*)d_ws + 16);
    long o = 0;
    ushort_t* detect_c = base + o; o += 16777216;   // (8,64,64,512)
    ushort_t* aim_c    = base + o; o += 4194304;    // (8,32,32,512)
    ushort_t* Wg_c   = base + o; o += 131072;
    ushort_t* Wt_c   = base + o; o += 131072;
    ushort_t* Wp_c   = base + o; o += 131072;
    ushort_t* Ww_c   = base + o; o += 131072;
    ushort_t* Wq_c   = base + o; o += 131072;
    ushort_t* bg_c   = base + o; o += 256;
    ushort_t* bt_c   = base + o; o += 256;
    ushort_t* bp_c   = base + o; o += 256;
    ushort_t* bw_c   = base + o; o += 512;
    ushort_t* gw_c   = base + o; o += 512;
    ushort_t* betw_c = base + o; o += 512;
    ushort_t* mw_c   = base + o; o += 512;
    ushort_t* vw_c   = base + o; o += 512;
    ushort_t* bq_c   = base + o; o += 512;
    ushort_t* gq_c   = base + o; o += 512;
    ushort_t* betq_c = base + o; o += 512;
    ushort_t* mq_c   = base + o; o += 512;
    ushort_t* vq_c   = base + o; o += 512;
    ushort_t* d_x    = base + o; o += 8388608;
    ushort_t* phi    = base + o; o += 8388608;
    ushort_t* a_x    = base + o; o += 2097152;
    ushort_t* theta  = base + o; o += 2097152;
    ushort_t* G1     = base + o; o += 524288;
    ushort_t* G2     = base + o; o += 524288;
    ushort_t* na     = base + o; o += 2097152;
    ushort_t* nd     = base + o; o += 8388608;    // total ~91 MB

    sniff_kernel<<<1, 64, 0, stream>>>((const uint32*)d_in[0], flag);

    struct Cv { int idx; ushort_t* dst; long n; int grid; } cv[20] = {
        {0, detect_c, 16777216, 2048}, {1, aim_c, 4194304, 1024},
        {2, Wg_c, 131072, 128}, {3, bg_c, 256, 1},
        {4, Wt_c, 131072, 128}, {5, bt_c, 256, 1},
        {6, Wp_c, 131072, 128}, {7, bp_c, 256, 1},
        {8, Ww_c, 131072, 128}, {9, bw_c, 512, 1},
        {10, gw_c, 512, 1}, {11, betw_c, 512, 1}, {12, mw_c, 512, 1}, {13, vw_c, 512, 1},
        {14, Wq_c, 131072, 128}, {15, bq_c, 512, 1},
        {16, gq_c, 512, 1}, {17, betq_c, 512, 1}, {18, mq_c, 512, 1}, {19, vq_c, 512, 1},
    };
    for (int i = 0; i < 20; i++)
        canon_kernel<<<cv[i].grid, 256, 0, stream>>>(d_in[cv[i].idx], cv[i].dst, cv[i].n, flag);

    const dim3 blk(256);
    const ushort_t* np = nullptr;

    gemm_kernel<false, false, EPI_BIAS, false><<<dim3(2, 256, 1), blk, 0, stream>>>(
        detect_c, Wg_c, d_x, 0, 32768, 256, 512, 512, 256, 256, 0, 0, 0,
        bg_c, np, np, np, np, np, 1.f, flag);
    gemm_kernel<false, false, EPI_BIAS, false><<<dim3(2, 64, 1), blk, 0, stream>>>(
        aim_c, Wg_c, a_x, 0, 8192, 256, 512, 512, 256, 256, 0, 0, 0,
        bg_c, np, np, np, np, np, 1.f, flag);
    gemm_kernel<false, false, EPI_BIAS, false><<<dim3(2, 64, 1), blk, 0, stream>>>(
        aim_c, Wt_c, theta, 0, 8192, 256, 512, 512, 256, 256, 0, 0, 0,
        bt_c, np, np, np, np, np, 1.f, flag);
    gemm_kernel<false, false, EPI_BIAS, false><<<dim3(2, 256, 1), blk, 0, stream>>>(
        detect_c, Wp_c, phi, 0, 32768, 256, 512, 512, 256, 256, 0, 0, 0,
        bp_c, np, np, np, np, np, 1.f, flag);

    gemm_kernel<true, false, EPI_PLAIN, false><<<dim3(2, 2, 8), blk, 0, stream>>>(
        phi, d_x, G1, 0, 256, 256, 4096, 256, 256, 256,
        4096L * 256, 4096L * 256, 256L * 256,
        np, np, np, np, np, np, 1.f, flag);

    gemm_kernel<true, false, EPI_PLAIN, false><<<dim3(2, 2, 8), blk, 0, stream>>>(
        theta, a_x, G2, 0, 256, 256, 1024, 256, 256, 256,
        1024L * 256, 1024L * 256, 256L * 256,
        np, np, np, np, np, np, 1.f, flag);

    gemm_kernel<false, false, EPI_SCALE, false><<<dim3(2, 8, 8), blk, 0, stream>>>(
        theta, G1, na, 0, 1024, 256, 256, 256, 256, 256,
        1024L * 256, 256L * 256, 1024L * 256,
        np, np, np, np, np, np, 1.f / 4096.f, flag);

    gemm_kernel<false, false, EPI_SCALE, false><<<dim3(2, 32, 8), blk, 0, stream>>>(
        phi, G2, nd, 0, 4096, 256, 256, 256, 256, 256,
        4096L * 256, 256L * 256, 4096L * 256,
        np, np, np, np, np, np, 1.f / 1024.f, flag);

    gemm_kernel<false, false, EPI_BN, true><<<dim3(4, 64, 1), blk, 0, stream>>>(
        na, Ww_c, d_out, 0, 8192, 512, 256, 256, 512, 512, 0, 0, 0,
        bw_c, gw_c, betw_c, mw_c, vw_c, aim_c, 1.f, flag);

    gemm_kernel<false, false, EPI_BN, true><<<dim3(4, 256, 1), blk, 0, stream>>>(
        nd, Wq_c, d_out, 8192L * 512, 32768, 512, 256, 256, 512, 512, 0, 0, 0,
        bq_c, gq_c, betq_c, mq_c, vq_c, detect_c, 1.f, flag);
}

// Round 4
// 477.512 us; speedup vs baseline: 1.3216x; 1.3216x over previous
//
#include <hip/hip_runtime.h>

typedef unsigned short ushort_t;
typedef unsigned int uint32;
typedef __bf16 bf16x8 __attribute__((ext_vector_type(8)));
typedef float f32x4 __attribute__((ext_vector_type(4)));
typedef uint32 u32x4 __attribute__((ext_vector_type(4)));
typedef uint32 u32x2 __attribute__((ext_vector_type(2)));

__device__ __forceinline__ float bf2f(ushort_t u) {
    uint32 x = ((uint32)u) << 16;
    return __builtin_bit_cast(float, x);
}
__device__ __forceinline__ ushort_t f2bf(float f) {
    uint32 x = __builtin_bit_cast(uint32, f);
    x += 0x7fffu + ((x >> 16) & 1u);   // RNE
    return (ushort_t)(x >> 16);
}

// dtype sniffer (validated r3): 1 = f32 inputs, 0 = bf16 inputs
__global__ void sniff_kernel(const uint32* __restrict__ src, int* __restrict__ flag) {
    __shared__ int cnt;
    if (threadIdx.x == 0) cnt = 0;
    __syncthreads();
    int weird = 0;
    for (int c = 0; c < 4; c++) {
        uint32 w = src[threadIdx.x * 4 + c];
        uint32 e = (w >> 7) & 0xFFu;
        weird += (e < 64u) || (e >= 192u);
    }
    atomicAdd(&cnt, weird);
    __syncthreads();
    if (threadIdx.x == 0) *flag = (cnt > 32) ? 1 : 0;
}

// big plain canon (validated r3)
__global__ void canon_kernel(const void* __restrict__ src, ushort_t* __restrict__ dst,
                             long n, const int* __restrict__ flag) {
    const bool isf32 = (*flag != 0);
    long i = (long)blockIdx.x * blockDim.x + threadIdx.x;
    const long stride = (long)gridDim.x * blockDim.x;
    if (isf32) {
        const float* s = (const float*)src;
        for (; i < n; i += stride) dst[i] = f2bf(s[i]);
    } else {
        const ushort_t* s = (const ushort_t*)src;
        for (; i < n; i += stride) dst[i] = s[i];
    }
}

// fused small-vector canon: 13 arrays in one launch
struct VecArgs { const void* s[13]; ushort_t* d[13]; int n[13]; };
__global__ void vec_canon_kernel(VecArgs a, const int* __restrict__ flag) {
    const bool isf32 = (*flag != 0);
    const int t = threadIdx.x;
    for (int seg = 0; seg < 13; seg++) {
        const int n = a.n[seg];
        if (isf32) {
            const float* s = (const float*)a.s[seg];
            for (int i = t; i < n; i += 256) a.d[seg][i] = f2bf(s[i]);
        } else {
            const ushort_t* s = (const ushort_t*)a.s[seg];
            for (int i = t; i < n; i += 256) a.d[seg][i] = s[i];
        }
    }
}

// transpose-canon: dst[C][R] = src[R][C], bf16 out, runtime src dtype.
__global__ void wt_canon_kernel(const void* __restrict__ src, ushort_t* __restrict__ dst,
                                int R, int C, const int* __restrict__ flag) {
    __shared__ float s[32][33];
    const bool isf32 = (*flag != 0);
    const int t = threadIdx.x;
    const int tr = blockIdx.y, tc = blockIdx.x;
    const int r = t >> 3, c4 = (t & 7) * 4;
    const long sbase = (long)(tr * 32 + r) * C + tc * 32 + c4;
    if (isf32) {
        const float* S = (const float*)src;
        const f32x4 v = *(const f32x4*)(S + sbase);
        for (int u = 0; u < 4; u++) s[r][c4 + u] = v[u];
    } else {
        const ushort_t* S = (const ushort_t*)src;
        for (int u = 0; u < 4; u++) s[r][c4 + u] = bf2f(S[sbase + u]);
    }
    __syncthreads();
    ushort_t tmp[4];
    for (int u = 0; u < 4; u++) tmp[u] = f2bf(s[c4 + u][r]);
    u32x2 pk;
    pk[0] = (uint32)tmp[0] | ((uint32)tmp[1] << 16);
    pk[1] = (uint32)tmp[2] | ((uint32)tmp[3] << 16);
    *(u32x2*)(dst + (long)(tc * 32 + r) * R + tr * 32 + c4) = pk;
}

// reduce 4 fp32 split-K partials + transposed bf16 store:
// out[b][n][m] = bf16( sum_{kc<4} P[(b*4+kc)*65536 + m*256 + n] )
__global__ void reduce_t_kernel(const float* __restrict__ P, ushort_t* __restrict__ out) {
    __shared__ float s[32][33];
    const int b = blockIdx.z, tm = blockIdx.y, tn = blockIdx.x;
    const int t = threadIdx.x;
    const int r = t >> 3, c4 = (t & 7) * 4;
    const float* base = P + (long)b * 4 * 65536 + (long)(tm * 32 + r) * 256 + tn * 32 + c4;
    f32x4 acc = {0.f, 0.f, 0.f, 0.f};
    for (int kc = 0; kc < 4; kc++) acc += *(const f32x4*)(base + (long)kc * 65536);
    for (int u = 0; u < 4; u++) s[r][c4 + u] = acc[u];
    __syncthreads();
    ushort_t tmp[4];
    for (int u = 0; u < 4; u++) tmp[u] = f2bf(s[c4 + u][r]);
    u32x2 pk;
    pk[0] = (uint32)tmp[0] | ((uint32)tmp[1] << 16);
    pk[1] = (uint32)tmp[2] | ((uint32)tmp[3] << 16);
    *(u32x2*)(out + (long)b * 65536 + (long)(tn * 32 + r) * 256 + tm * 32 + c4) = pk;
}

#define BM 128
#define BN 128
#define BK 32
#define LDSS 40

enum { EPI_BIAS = 0, EPI_BIASR = 1, EPI_SCALE = 2, EPI_BN = 3, EPI_PART = 4 };

// NT GEMM: C[m][n] = sum_k A[m][k] * B[n][k], both operands k-contiguous.
// Grid covers exactly (N/BN, M/BM, Z). Per-z offsets: A+=z*sA, B+=z*sB, cbase=coff+z*sC.
// EPI_PART: fp32 store (split-K partial). DUALT: also store bf16 C^T at CT (ldT).
template <int EPI, bool DYNOUT, bool DUALT>
__global__ __launch_bounds__(256) void gemm_nt(
    const ushort_t* __restrict__ A, const ushort_t* __restrict__ B,
    void* __restrict__ Cv, long coff,
    int K, int lda, int ldb, int ldc,
    long sA, long sB, long sC,
    ushort_t* __restrict__ CT, int ldT,
    const ushort_t* __restrict__ bias,
    const ushort_t* __restrict__ gamma, const ushort_t* __restrict__ beta,
    const ushort_t* __restrict__ mean, const ushort_t* __restrict__ var,
    const ushort_t* __restrict__ res,
    float alpha, const int* __restrict__ flag)
{
    __shared__ __align__(16) ushort_t As[BM * LDSS];
    __shared__ __align__(16) ushort_t Bs[BN * LDSS];

    const bool isf32 = DYNOUT ? (*flag != 0) : false;

    const int z = blockIdx.z;
    A += (long)z * sA;
    B += (long)z * sB;
    const long cbase = coff + (long)z * sC;

    const int tid  = threadIdx.x;
    const int lane = tid & 63;
    const int w    = tid >> 6;
    const int wr   = w >> 1, wc = w & 1;
    const int lr   = lane & 15, q = lane >> 4;

    const int m0 = blockIdx.y * BM;
    const int n0 = blockIdx.x * BN;

    f32x4 acc[4][4];
#pragma unroll
    for (int i = 0; i < 4; i++)
#pragma unroll
        for (int j = 0; j < 4; j++) acc[i][j] = (f32x4){0.f, 0.f, 0.f, 0.f};

    for (int k0 = 0; k0 < K; k0 += BK) {
#pragma unroll
        for (int c = 0; c < 2; c++) {
            const int ch = tid + c * 256;
            const int r = ch >> 2, qq = ch & 3;
            *(u32x4*)(&As[r * LDSS + qq * 8]) =
                *(const u32x4*)(A + (long)(m0 + r) * lda + k0 + qq * 8);
        }
#pragma unroll
        for (int c = 0; c < 2; c++) {
            const int ch = tid + c * 256;
            const int r = ch >> 2, qq = ch & 3;
            *(u32x4*)(&Bs[r * LDSS + qq * 8]) =
                *(const u32x4*)(B + (long)(n0 + r) * ldb + k0 + qq * 8);
        }
        __syncthreads();

        bf16x8 af[4], bfr[4];
#pragma unroll
        for (int i = 0; i < 4; i++)
            af[i] = __builtin_bit_cast(bf16x8,
                *(const u32x4*)(&As[(wr * 64 + i * 16 + lr) * LDSS + q * 8]));
#pragma unroll
        for (int j = 0; j < 4; j++)
            bfr[j] = __builtin_bit_cast(bf16x8,
                *(const u32x4*)(&Bs[(wc * 64 + j * 16 + lr) * LDSS + q * 8]));
#pragma unroll
        for (int i = 0; i < 4; i++)
#pragma unroll
            for (int j = 0; j < 4; j++)
                acc[i][j] = __builtin_amdgcn_mfma_f32_16x16x32_bf16(af[i], bfr[j], acc[i][j], 0, 0, 0);
        __syncthreads();
    }

    // D layout: col=lane&15, row=(lane>>4)*4+reg  [verified]
#pragma unroll
    for (int j = 0; j < 4; j++) {
        const int col = n0 + wc * 64 + j * 16 + lr;
        float bs = 0.f, sc = 1.f, sh = 0.f;
        if constexpr (EPI == EPI_BIAS || EPI == EPI_BN) bs = bf2f(bias[col]);
        if constexpr (EPI == EPI_BN) {
            const float g  = bf2f(gamma[col]);
            const float bt = bf2f(beta[col]);
            const float mn = bf2f(mean[col]);
            const float vr = bf2f(var[col]);
            sc = g * rsqrtf(vr + 1e-3f);
            sh = bt - sc * mn;
        }
#pragma unroll
        for (int i = 0; i < 4; i++) {
            const int rowbase = m0 + wr * 64 + i * 16 + q * 4;
            ushort_t tmp[4];
#pragma unroll
            for (int r = 0; r < 4; r++) {
                const int row = rowbase + r;
                float v = acc[i][j][r];
                if constexpr (EPI == EPI_BIAS) v += bs;
                else if constexpr (EPI == EPI_BIASR) v += bf2f(bias[row]);
                else if constexpr (EPI == EPI_SCALE) v *= alpha;
                else if constexpr (EPI == EPI_BN)
                    v = sc * (v + bs) + sh + bf2f(res[(long)row * ldc + col]);
                const long off = cbase + (long)row * ldc + col;
                if constexpr (EPI == EPI_PART) {
                    ((float*)Cv)[off] = v;
                } else if constexpr (DYNOUT) {
                    if (isf32) ((float*)Cv)[off] = v;
                    else       ((ushort_t*)Cv)[off] = f2bf(v);
                } else {
                    const ushort_t us = f2bf(v);
                    ((ushort_t*)Cv)[off] = us;
                    if constexpr (DUALT) tmp[r] = us;
                }
            }
            if constexpr (DUALT) {
                u32x2 pk;
                pk[0] = (uint32)tmp[0] | ((uint32)tmp[1] << 16);
                pk[1] = (uint32)tmp[2] | ((uint32)tmp[3] << 16);
                *(u32x2*)(CT + (long)col * ldT + rowbase) = pk;
            }
        }
    }
}

extern "C" void kernel_launch(void* const* d_in, const int* in_sizes, int n_in,
                              void* d_out, int out_size, void* d_ws, size_t ws_size,
                              hipStream_t stream)
{
    int* flag = (int*)d_ws;
    ushort_t* base = (ushort_t*)((char*)d_ws + 16);
    long o = 0;
    ushort_t* detect_c = base + o; o += 16777216;   // [32768][512]
    ushort_t* aim_c    = base + o; o += 4194304;    // [8192][512]
    ushort_t* WgT  = base + o; o += 131072;         // [256][512]
    ushort_t* WtT  = base + o; o += 131072;
    ushort_t* WpT  = base + o; o += 131072;
    ushort_t* WwT  = base + o; o += 131072;         // [512][256]
    ushort_t* WqT  = base + o; o += 131072;
    ushort_t* bg_c   = base + o; o += 256;
    ushort_t* bt_c   = base + o; o += 256;
    ushort_t* bp_c   = base + o; o += 256;
    ushort_t* bw_c   = base + o; o += 512;
    ushort_t* gw_c   = base + o; o += 512;
    ushort_t* betw_c = base + o; o += 512;
    ushort_t* mw_c   = base + o; o += 512;
    ushort_t* vw_c   = base + o; o += 512;
    ushort_t* bq_c   = base + o; o += 512;
    ushort_t* gq_c   = base + o; o += 512;
    ushort_t* betq_c = base + o; o += 512;
    ushort_t* mq_c   = base + o; o += 512;
    ushort_t* vq_c   = base + o; o += 512;
    ushort_t* phi    = base + o; o += 8388608;      // [32768][256]
    ushort_t* phiT   = base + o; o += 8388608;      // [256][32768]
    ushort_t* d_xT   = base + o; o += 8388608;      // [256][32768]
    ushort_t* theta  = base + o; o += 2097152;      // [8192][256]
    ushort_t* thetaT = base + o; o += 2097152;      // [256][8192]
    ushort_t* a_xT   = base + o; o += 2097152;      // [256][8192]
    ushort_t* G1T    = base + o; o += 524288;       // [8][256][256]
    ushort_t* G2T    = base + o; o += 524288;
    // union region: P1,P2 (fp32, lifetime ends at reduces) then na,nd
    ushort_t* U      = base + o; o += 10485760;     // 21 MB
    float* P1 = (float*)U;                          // 32 x 65536 fp32
    float* P2 = P1 + 2097152;
    ushort_t* na = U;                               // [8192][256]
    ushort_t* nd = na + 2097152;                    // [32768][256]
    // total ~123 MiB

    sniff_kernel<<<1, 64, 0, stream>>>((const uint32*)d_in[0], flag);

    // canon: vectors (fused), weights (transposed), activations (plain)
    VecArgs va;
    const int vidx[13] = {3, 5, 7, 9, 10, 11, 12, 13, 15, 16, 17, 18, 19};
    ushort_t* vdst[13] = {bg_c, bt_c, bp_c, bw_c, gw_c, betw_c, mw_c, vw_c,
                          bq_c, gq_c, betq_c, mq_c, vq_c};
    const int vn[13] = {256, 256, 256, 512, 512, 512, 512, 512, 512, 512, 512, 512, 512};
    for (int i = 0; i < 13; i++) { va.s[i] = d_in[vidx[i]]; va.d[i] = vdst[i]; va.n[i] = vn[i]; }
    vec_canon_kernel<<<1, 256, 0, stream>>>(va, flag);

    wt_canon_kernel<<<dim3(8, 16), 256, 0, stream>>>(d_in[2], WgT, 512, 256, flag);
    wt_canon_kernel<<<dim3(8, 16), 256, 0, stream>>>(d_in[4], WtT, 512, 256, flag);
    wt_canon_kernel<<<dim3(8, 16), 256, 0, stream>>>(d_in[6], WpT, 512, 256, flag);
    wt_canon_kernel<<<dim3(16, 8), 256, 0, stream>>>(d_in[8], WwT, 256, 512, flag);
    wt_canon_kernel<<<dim3(16, 8), 256, 0, stream>>>(d_in[14], WqT, 256, 512, flag);
    canon_kernel<<<2048, 256, 0, stream>>>(d_in[0], detect_c, 16777216, flag);
    canon_kernel<<<1024, 256, 0, stream>>>(d_in[1], aim_c, 4194304, flag);

    const dim3 blk(256);
    const ushort_t* np = nullptr;
    ushort_t* npm = nullptr;

    // conv phi: [32768][256] + dual-T [256][32768]
    gemm_nt<EPI_BIAS, false, true><<<dim3(2, 256, 1), blk, 0, stream>>>(
        detect_c, WpT, phi, 0, 512, 512, 512, 256, 0, 0, 0,
        phiT, 32768, bp_c, np, np, np, np, np, 1.f, flag);
    // conv theta: [8192][256] + dual-T [256][8192]
    gemm_nt<EPI_BIAS, false, true><<<dim3(2, 64, 1), blk, 0, stream>>>(
        aim_c, WtT, theta, 0, 512, 512, 512, 256, 0, 0, 0,
        thetaT, 8192, bt_c, np, np, np, np, np, 1.f, flag);
    // conv d_xT (transposed orientation): C[ci][spatial], row-bias
    gemm_nt<EPI_BIASR, false, false><<<dim3(256, 2, 1), blk, 0, stream>>>(
        WgT, detect_c, d_xT, 0, 512, 512, 512, 32768, 0, 0, 0,
        npm, 0, bg_c, np, np, np, np, np, 1.f, flag);
    // conv a_xT
    gemm_nt<EPI_BIASR, false, false><<<dim3(64, 2, 1), blk, 0, stream>>>(
        WgT, aim_c, a_xT, 0, 512, 512, 512, 8192, 0, 0, 0,
        npm, 0, bg_c, np, np, np, np, np, 1.f, flag);

    // G1 partials: z=b*4+kc, K-chunk 1024; offset = z*1024 (batch stride 4096 = 4*1024)
    gemm_nt<EPI_PART, false, false><<<dim3(2, 2, 32), blk, 0, stream>>>(
        phiT, d_xT, P1, 0, 1024, 32768, 32768, 256, 1024, 1024, 65536,
        npm, 0, np, np, np, np, np, np, 1.f, flag);
    // G2 partials: K-chunk 256 (batch stride 1024 = 4*256)
    gemm_nt<EPI_PART, false, false><<<dim3(2, 2, 32), blk, 0, stream>>>(
        thetaT, a_xT, P2, 0, 256, 8192, 8192, 256, 256, 256, 65536,
        npm, 0, np, np, np, np, np, np, 1.f, flag);

    reduce_t_kernel<<<dim3(8, 8, 8), blk, 0, stream>>>(P1, G1T);
    reduce_t_kernel<<<dim3(8, 8, 8), blk, 0, stream>>>(P2, G2T);

    // na = theta @ G1 / 4096  (B = G1T, NT)
    gemm_nt<EPI_SCALE, false, false><<<dim3(2, 8, 8), blk, 0, stream>>>(
        theta, G1T, na, 0, 256, 256, 256, 256, 262144, 65536, 262144,
        npm, 0, np, np, np, np, np, np, 1.f / 4096.f, flag);
    // nd = phi @ G2 / 1024
    gemm_nt<EPI_SCALE, false, false><<<dim3(2, 32, 8), blk, 0, stream>>>(
        phi, G2T, nd, 0, 256, 256, 256, 256, 1048576, 65536, 1048576,
        npm, 0, np, np, np, np, np, np, 1.f / 1024.f, flag);

    // out0 = BN(na @ Ww + bw) + aim
    gemm_nt<EPI_BN, true, false><<<dim3(4, 64, 1), blk, 0, stream>>>(
        na, WwT, d_out, 0, 256, 256, 256, 512, 0, 0, 0,
        npm, 0, bw_c, gw_c, betw_c, mw_c, vw_c, aim_c, 1.f, flag);
    // out1 = BN(nd @ Wq + bq) + detect
    gemm_nt<EPI_BN, true, false><<<dim3(4, 256, 1), blk, 0, stream>>>(
        nd, WqT, d_out, 8192L * 512, 256, 256, 256, 512, 0, 0, 0,
        npm, 0, bq_c, gq_c, betq_c, mq_c, vq_c, detect_c, 1.f, flag);
}